// Round 15
// baseline (34357.156 us; speedup 1.0000x reference)
//
#include <hip/hip_runtime.h>
#include <hip/hip_bf16.h>
#include <math.h>

// Problem constants (fixed by the reference)
#define T_STEPS 4096
#define N_IN    8192
#define N_OUT   2048

// ---------------------------------------------------------------------------
// FUSED kernel, v15 = wave-independent ESN + r12's concentrated GEMM.
//   Blocks [0,64): ESN. Each of the 4 waves is fully self-sufficient per
//   step: it polls ALL 2048 tagged slots (32/lane, coalesced 8B), stages
//   arrivals into its PRIVATE single-buffer vsh (8KB/wave; wave-internal DS
//   ordering), then MACs its 8 columns from register-resident W entries.
//   NO __syncthreads in the hot loop -> no intra-block lockstep coupling.
//   Poll-traffic 4x is pre-measured benign (r2 at 524K loads/round == r4 at
//   131K). Single-buffer vsh safe: step-t gathers are issued before step-t+1
//   staging writes (in-order per-wave DS pipe).
//   Rotation safety (2-deep, wave-level): a wave stores v_{t+1} only after
//   reading ALL of v_t => every wave finished its v_{t-1} poll => the
//   parity buffer being overwritten has no readers.
//   Blocks [64,576): GEMM, one 128x128 tile each (r12 layout — r14 showed the
//   concentrated burst beats a spread-out persistent GEMM). LDS now 73.9KB
//   -> GEMM gets 2 blocks/CU (was 1 in r12): even shorter burst.
//   Verified pieces kept: pads-last bank-rotation sort + kmw tail-skip (r14),
//   register leak term, u-prefetch BEFORE the poll (r11), setprio,
//   launch_bounds(256,1) (r10 spill lesson), mcnt m-tile gating.
// ---------------------------------------------------------------------------
#define RB    64    // esn blocks
#define CPB   32    // columns per esn block (8 per wave)
#define GRP   8     // lanes per column
#define CAP   288   // nnz capacity per column (mean 204.8, sigma 13.6)
#define KMAX  (CAP / GRP)   // 36 register entries per lane
#define NMT   32    // m-tiles (4096/128)
#define GEMM_BLOCKS 512     // one tile each (concentrated burst)
#define GM_BK 32

// ---- shared-memory overlay ------------------------------------------------
// esn setup:  ent[32][288] u64 = 73728 B, cnts = 128 B   (dead after setup)
// esn hot:    vsh_w[4][2048] f32 = 32768 B  (overlays ent region)
// gemm:       As[32][132]+Bs[32][132] = 33792 B
#define SM_CNTS  73728
#define SM_BYTES (73728 + 128)   // 73856 B -> 2 blocks/CU possible for GEMM
#define SM_GA    0
#define SM_GB    16896

__device__ __forceinline__ float fast_tanh(float x) {
    const float ax = fabsf(x);
    const float e  = __expf(2.0f * ax);               // inf for big ax
    const float r  = __builtin_amdgcn_rcpf(e + 1.0f); // rcp(inf)=0 -> tanh=1
    const float t  = 1.0f - 2.0f * r;
    return copysignf(t, x);
}

__global__ __launch_bounds__(256, 1) void esn_fused(
        const float* __restrict__ X,    // [4096, 8192]
        const float* __restrict__ W,    // [2048, 2048]
        const float* __restrict__ Win,  // [8192, 2048]
        float* __restrict__ UO,         // [4096, 2048] u_proj then states
        unsigned long long* vslots,     // 2 x N_OUT tagged slots
        int* mcnt) {                    // NMT m-tile completion counters
    __shared__ __align__(16) char smem[SM_BYTES];
    const int tid = threadIdx.x;

    if (blockIdx.x >= RB) {
        // ============ GEMM role: one 128x128 tile (r12 layout) =============
        float (*As)[132] = reinterpret_cast<float(*)[132]>(smem + SM_GA);
        float (*Bs)[132] = reinterpret_cast<float(*)[132]>(smem + SM_GB);
        const int gb = (int)blockIdx.x - RB;
        const int bm = gb >> 4;            // blocks 64..79 -> m-tile 0 first
        const int bn = gb & 15;
        const int K = N_IN, N = N_OUT;
        const int tx = tid & 15;
        const int ty = tid >> 4;

        float acc[8][8];
#pragma unroll
        for (int i = 0; i < 8; i++)
#pragma unroll
            for (int jj = 0; jj < 8; jj++) acc[i][jj] = 0.f;

        const float* Xb = X + (size_t)(bm * 128) * K;
        const float* Wb = Win + bn * 128;

        for (int kt = 0; kt < K; kt += GM_BK) {
#pragma unroll
            for (int q = 0; q < 4; q++) {
                const int r  = (tid >> 3) + q * 32;
                const int c4 = (tid & 7) * 4;
                const float4 a4 = *reinterpret_cast<const float4*>(&Xb[(size_t)r * K + kt + c4]);
                As[c4 + 0][r] = a4.x;
                As[c4 + 1][r] = a4.y;
                As[c4 + 2][r] = a4.z;
                As[c4 + 3][r] = a4.w;
            }
#pragma unroll
            for (int q = 0; q < 4; q++) {
                const int r  = (tid >> 5) + q * 8;
                const int c4 = (tid & 31) * 4;
                *reinterpret_cast<float4*>(&Bs[r][c4]) =
                    *reinterpret_cast<const float4*>(&Wb[(size_t)(kt + r) * N + c4]);
            }
            __syncthreads();

#pragma unroll
            for (int k = 0; k < GM_BK; k++) {
                float a[8], bb[8];
#pragma unroll
                for (int i = 0; i < 4; i++) {
                    a[i]     = As[k][ty * 4 + i];
                    a[4 + i] = As[k][64 + ty * 4 + i];
                }
#pragma unroll
                for (int jj = 0; jj < 4; jj++) {
                    bb[jj]     = Bs[k][tx * 4 + jj];
                    bb[4 + jj] = Bs[k][64 + tx * 4 + jj];
                }
#pragma unroll
                for (int i = 0; i < 8; i++)
#pragma unroll
                    for (int jj = 0; jj < 8; jj++)
                        acc[i][jj] = fmaf(a[i], bb[jj], acc[i][jj]);
            }
            __syncthreads();
        }

#pragma unroll
        for (int i = 0; i < 8; i++) {
            const int mr = bm * 128 + ((i < 4) ? (ty * 4 + i) : (64 + ty * 4 + (i - 4)));
            float* Crow = UO + (size_t)mr * N + bn * 128;
            float4 v0 = make_float4(acc[i][0], acc[i][1], acc[i][2], acc[i][3]);
            float4 v1 = make_float4(acc[i][4], acc[i][5], acc[i][6], acc[i][7]);
            *reinterpret_cast<float4*>(&Crow[tx * 4])      = v0;
            *reinterpret_cast<float4*>(&Crow[64 + tx * 4]) = v1;
        }
        __syncthreads();   // drains vmcnt(0): C-tile stores complete
        if (tid == 0)      // release makes the tile visible, then signals
            __hip_atomic_fetch_add(&mcnt[bm], 1, __ATOMIC_RELEASE,
                                   __HIP_MEMORY_SCOPE_AGENT);
        return;
    }

    // =================== ESN role: wave-independent ========================
    __builtin_amdgcn_s_setprio(1);
    auto ent  = reinterpret_cast<unsigned long long(*)[CAP]>(smem);
    int* cnts = reinterpret_cast<int*>(smem + SM_CNTS);

    const int b   = blockIdx.x;
    const int wv  = tid >> 6;              // wave 0..3
    const int lw  = tid & 63;              // lane within wave
    const int c   = tid >> 3;              // column group 0..31
    const int l   = tid & 7;               // lane within group
    const int j   = b * CPB + c;           // global output column

    // ---------- build sparse columns into LDS scratch (one-time) ----------
    int cnt = 0;
    for (int k = 0; k < N_OUT / GRP; k++) {
        const float w = W[(size_t)(l + GRP * k) * N_OUT + j];
        cnt += (w != 0.0f) ? 1 : 0;
    }
    int inc = cnt;
#pragma unroll
    for (int d = 1; d < GRP; d <<= 1) {
        int n = __shfl_up(inc, d, 64);
        if (l >= d) inc += n;
    }
    int pos = inc - cnt;
    if (l == GRP - 1) cnts[c] = inc;
    for (int k = 0; k < N_OUT / GRP; k++) {
        const int i = l + GRP * k;
        const float w = W[(size_t)i * N_OUT + j];
        if (w != 0.0f) {
            if (pos < CAP)
                ent[c][pos] = ((unsigned long long)(unsigned)i << 32) | __float_as_uint(w);
            pos++;
        }
    }
    __syncthreads();
    const int ccnt = min(cnts[c], CAP);

    // ---------- entries -> registers, padded to KMAX ----------
    float wreg[KMAX];
    int   ireg[KMAX];
#pragma unroll
    for (int k = 0; k < KMAX; k++) {
        const int p = l + k * GRP;
        if (p < ccnt) {
            const unsigned long long e = ent[c][p];
            wreg[k] = __uint_as_float((unsigned)e);
            ireg[k] = (int)(e >> 32);
        } else {
            wreg[k] = 0.f;   // pad: gathers vsh[0] (broadcast), w=0
            ireg[k] = 0;
        }
    }

    // wave-uniform MAC bound
    int kmw = (ccnt + GRP - 1) >> 3;
#pragma unroll
    for (int d = 1; d < 64; d <<= 1) {
        const int o = __shfl_xor(kmw, d, 64);
        kmw = (o > kmw) ? o : kmw;
    }
    if (kmw > KMAX) kmw = KMAX;

    // bank-rotation sort, pads last (r14-verified)
#pragma unroll
    for (int pass = 0; pass < KMAX; ++pass) {
#pragma unroll
        for (int i = (pass & 1); i + 1 < KMAX; i += 2) {
            const int ka = (wreg[i]     == 0.f) ? 64 : (((ireg[i]     & 31) - lw) & 31);
            const int kb = (wreg[i + 1] == 0.f) ? 64 : (((ireg[i + 1] & 31) - lw) & 31);
            const bool sw = ka > kb;
            const int   ti = sw ? ireg[i] : ireg[i + 1];
            const int   bi = sw ? ireg[i + 1] : ireg[i];
            const float tw = sw ? wreg[i] : wreg[i + 1];
            const float bw = sw ? wreg[i + 1] : wreg[i];
            ireg[i] = bi; ireg[i + 1] = ti;
            wreg[i] = bw; wreg[i + 1] = tw;
        }
    }

    __syncthreads();   // all reg-loads done: ent region may now be reused
    float* vshw = reinterpret_cast<float*>(smem) + wv * N_OUT;  // private 8KB
    float vold = 0.f;

    // ---------- sequential scan over T (NO barriers) ----------
#pragma unroll 1
    for (int t = 0; t < T_STEPS; t++) {
        // gate on the u-producer once per m-tile (wave-uniform, rare)
        if ((t & 127) == 0) {
            while (__hip_atomic_load(&mcnt[t >> 7], __ATOMIC_ACQUIRE,
                                     __HIP_MEMORY_SCOPE_AGENT) < 16) { }
        }
        // u prefetch BEFORE the poll: rides the poll's wait (r11)
        float u = 0.f;
        if (l == 0) u = UO[(size_t)t * N_OUT + j];

        // ---- poll ALL 2048 tagged slots: 32 coalesced 8B loads per lane ---
        const unsigned long long* vin = vslots + (size_t)(t & 1) * N_OUT;
        const unsigned ut = (unsigned)t;
        unsigned long long uq[32];
#pragma unroll
        for (int q = 0; q < 32; q++)
            uq[q] = __hip_atomic_load(&vin[lw + q * 64], __ATOMIC_RELAXED,
                                      __HIP_MEMORY_SCOPE_AGENT);
        unsigned pend = 0xFFFFFFFFu;
#pragma unroll 1
        while (true) {
            unsigned np = 0;
#pragma unroll
            for (int q = 0; q < 32; q++) {
                if (pend & (1u << q)) {
                    if ((unsigned)(uq[q] >> 32) == ut)
                        vshw[lw + q * 64] = __uint_as_float((unsigned)uq[q]);
                    else
                        np |= (1u << q);
                }
            }
            pend = np;
            if (!pend) break;    // lanes exit individually; wave reconverges
#pragma unroll
            for (int q = 0; q < 32; q++)
                if (pend & (1u << q))
                    uq[q] = __hip_atomic_load(&vin[lw + q * 64], __ATOMIC_RELAXED,
                                              __HIP_MEMORY_SCOPE_AGENT);
        }
        // wave-internal DS ordering: staging writes above complete before the
        // gathers below (in-order per-wave DS pipe) — no barrier needed.

        // ---- MAC: 20 unconditional + wave-uniform guarded tail chunks -----
        float yy[4] = {0.f, 0.f, 0.f, 0.f};
#define MACK(k) yy[(k) & 3] = fmaf(wreg[(k)], vshw[ireg[(k)]], yy[(k) & 3])
#pragma unroll
        for (int k = 0; k < 20; k += 4) {
            MACK(k + 0); MACK(k + 1); MACK(k + 2); MACK(k + 3);
        }
        if (kmw > 20) { MACK(20); MACK(21); MACK(22); MACK(23); }
        if (kmw > 24) { MACK(24); MACK(25); MACK(26); MACK(27); }
        if (kmw > 28) { MACK(28); MACK(29); MACK(30); MACK(31); }
        if (kmw > 32) { MACK(32); MACK(33); MACK(34); MACK(35); }
#undef MACK
        float y = (yy[0] + yy[1]) + (yy[2] + yy[3]);
#pragma unroll
        for (int d = GRP / 2; d >= 1; d >>= 1) y += __shfl_xor(y, d, 64);

        if (l == 0) {
            const float vnew = 0.5f * vold + 0.5f * fast_tanh(y + u);
            vold = vnew;
            // slot store FIRST (inter-block critical path), then the output
            const unsigned long long slot =
                ((unsigned long long)(unsigned)(t + 1) << 32) | __float_as_uint(vnew);
            __hip_atomic_store(&vslots[(size_t)((t + 1) & 1) * N_OUT + j], slot,
                               __ATOMIC_RELAXED, __HIP_MEMORY_SCOPE_AGENT);
            UO[(size_t)t * N_OUT + j] = vnew;
        }
    }
}

// ---------------------------------------------------------------------------
extern "C" void kernel_launch(void* const* d_in, const int* in_sizes, int n_in,
                              void* d_out, int out_size, void* d_ws, size_t ws_size,
                              hipStream_t stream) {
    const float* x   = (const float*)d_in[0];   // [4096, 8192]
    const float* W   = (const float*)d_in[1];   // [2048, 2048]
    const float* Win = (const float*)d_in[2];   // [8192, 2048]
    float* out = (float*)d_out;                 // [4096, 2048]

    unsigned long long* vslots = (unsigned long long*)d_ws;  // 2 x N_OUT x 8B
    int* mcnt = (int*)((char*)d_ws + 2 * N_OUT * sizeof(unsigned long long));

    // zero slots (tag0 = zero state) + m-tile counters, every launch
    hipMemsetAsync(d_ws, 0,
                   2 * N_OUT * sizeof(unsigned long long) + NMT * sizeof(int),
                   stream);

    esn_fused<<<RB + GEMM_BLOCKS, 256, 0, stream>>>(x, W, Win, out, vslots, mcnt);
}

// Round 16
// 11278.013 us; speedup vs baseline: 3.0464x; 3.0464x over previous
//
#include <hip/hip_runtime.h>
#include <hip/hip_bf16.h>
#include <math.h>

// Problem constants (fixed by the reference)
#define T_STEPS 4096
#define N_IN    8192
#define N_OUT   2048

// ---------------------------------------------------------------------------
// FUSED kernel, v16 = CONSOLIDATION of the two verified-best halves:
//   - r12's GEMM: blocks [64,576), one 128x128 tile each (concentrated burst;
//     r14 proved spreading it out is worse). BK=32.
//   - r14's ESN hot loop (verified: conflicts 2.07e8 -> 1.79e8, correct):
//     r9 structure (64 blocks x 4 waves, staged poll, ONE barrier/step)
//     + W entries in registers + pads-LAST bank-rotation sort + kmw tail-skip
//     + register leak term + u-prefetch BEFORE the poll (r11 lesson)
//     + setprio(1), launch_bounds(256,1) (r10 spill lesson), mcnt gating.
//   Design-family conclusion from r2/r4/r7/r8/r15: 64x4-wave staged poll with
//   a single barrier is the optimum shape; more wave independence (r7/r15)
//   and fewer readers (r4/r8) both lose.
// ---------------------------------------------------------------------------
#define RB    64    // esn blocks
#define CPB   32    // columns per esn block
#define GRP   8     // lanes per column
#define CAP   288   // nnz capacity per column (mean 204.8, sigma 13.6)
#define KMAX  (CAP / GRP)   // 36 register entries per lane
#define NMT   32    // m-tiles (4096/128)
#define GEMM_BLOCKS 512     // one tile each (concentrated burst)
#define GM_BK 32

// ---- shared-memory overlay (roles never coexist within a block) ----------
#define SM_ENT   0                        // u64 ent[CPB][CAP] = 73728 B
#define SM_CNTS  73728                    // int cnts[CPB] (+pad) = 128 B
#define SM_VSH   (73728 + 128)            // f32 vsh[2][N_OUT] = 16384 B
#define SM_BYTES (73728 + 128 + 16384)    // 90240 B
#define SM_GA    0                        // f32 As[32][132] = 16896 B
#define SM_GB    16896                    // f32 Bs[32][132] = 16896 B

__device__ __forceinline__ float fast_tanh(float x) {
    const float ax = fabsf(x);
    const float e  = __expf(2.0f * ax);               // inf for big ax
    const float r  = __builtin_amdgcn_rcpf(e + 1.0f); // rcp(inf)=0 -> tanh=1
    const float t  = 1.0f - 2.0f * r;
    return copysignf(t, x);
}

__global__ __launch_bounds__(256, 1) void esn_fused(
        const float* __restrict__ X,    // [4096, 8192]
        const float* __restrict__ W,    // [2048, 2048]
        const float* __restrict__ Win,  // [8192, 2048]
        float* __restrict__ UO,         // [4096, 2048] u_proj then states
        unsigned long long* vslots,     // 2 x N_OUT tagged slots
        int* mcnt) {                    // NMT m-tile completion counters
    __shared__ __align__(16) char smem[SM_BYTES];
    const int tid = threadIdx.x;

    if (blockIdx.x >= RB) {
        // ============ GEMM role: one 128x128 tile (r12 layout) =============
        float (*As)[132] = reinterpret_cast<float(*)[132]>(smem + SM_GA);
        float (*Bs)[132] = reinterpret_cast<float(*)[132]>(smem + SM_GB);
        const int gb = (int)blockIdx.x - RB;
        const int bm = gb >> 4;            // blocks 64..79 -> m-tile 0 first
        const int bn = gb & 15;
        const int K = N_IN, N = N_OUT;
        const int tx = tid & 15;
        const int ty = tid >> 4;

        float acc[8][8];
#pragma unroll
        for (int i = 0; i < 8; i++)
#pragma unroll
            for (int jj = 0; jj < 8; jj++) acc[i][jj] = 0.f;

        const float* Xb = X + (size_t)(bm * 128) * K;
        const float* Wb = Win + bn * 128;

        for (int kt = 0; kt < K; kt += GM_BK) {
#pragma unroll
            for (int q = 0; q < 4; q++) {
                const int r  = (tid >> 3) + q * 32;
                const int c4 = (tid & 7) * 4;
                const float4 a4 = *reinterpret_cast<const float4*>(&Xb[(size_t)r * K + kt + c4]);
                As[c4 + 0][r] = a4.x;
                As[c4 + 1][r] = a4.y;
                As[c4 + 2][r] = a4.z;
                As[c4 + 3][r] = a4.w;
            }
#pragma unroll
            for (int q = 0; q < 4; q++) {
                const int r  = (tid >> 5) + q * 8;
                const int c4 = (tid & 31) * 4;
                *reinterpret_cast<float4*>(&Bs[r][c4]) =
                    *reinterpret_cast<const float4*>(&Wb[(size_t)(kt + r) * N + c4]);
            }
            __syncthreads();

#pragma unroll
            for (int k = 0; k < GM_BK; k++) {
                float a[8], bb[8];
#pragma unroll
                for (int i = 0; i < 4; i++) {
                    a[i]     = As[k][ty * 4 + i];
                    a[4 + i] = As[k][64 + ty * 4 + i];
                }
#pragma unroll
                for (int jj = 0; jj < 4; jj++) {
                    bb[jj]     = Bs[k][tx * 4 + jj];
                    bb[4 + jj] = Bs[k][64 + tx * 4 + jj];
                }
#pragma unroll
                for (int i = 0; i < 8; i++)
#pragma unroll
                    for (int jj = 0; jj < 8; jj++)
                        acc[i][jj] = fmaf(a[i], bb[jj], acc[i][jj]);
            }
            __syncthreads();
        }

#pragma unroll
        for (int i = 0; i < 8; i++) {
            const int mr = bm * 128 + ((i < 4) ? (ty * 4 + i) : (64 + ty * 4 + (i - 4)));
            float* Crow = UO + (size_t)mr * N + bn * 128;
            float4 v0 = make_float4(acc[i][0], acc[i][1], acc[i][2], acc[i][3]);
            float4 v1 = make_float4(acc[i][4], acc[i][5], acc[i][6], acc[i][7]);
            *reinterpret_cast<float4*>(&Crow[tx * 4])      = v0;
            *reinterpret_cast<float4*>(&Crow[64 + tx * 4]) = v1;
        }
        __syncthreads();   // drains vmcnt(0): C-tile stores complete
        if (tid == 0)      // release makes the tile visible, then signals
            __hip_atomic_fetch_add(&mcnt[bm], 1, __ATOMIC_RELEASE,
                                   __HIP_MEMORY_SCOPE_AGENT);
        return;
    }

    // ======================= ESN recurrence role (r14) ======================
    __builtin_amdgcn_s_setprio(1);   // esn waves win issue arbitration
    auto ent  = reinterpret_cast<unsigned long long(*)[CAP]>(smem + SM_ENT);
    int* cnts = reinterpret_cast<int*>(smem + SM_CNTS);
    float (*vsh)[N_OUT] = reinterpret_cast<float(*)[N_OUT]>(smem + SM_VSH);

    const int b   = blockIdx.x;
    const int c   = tid >> 3;              // column group 0..31
    const int l   = tid & 7;               // lane within group
    const int j   = b * CPB + c;           // global output column
    const int lw  = tid & 63;              // lane within wave (bank rotation)

    // ---------- build sparse column into LDS scratch (one-time) ----------
    int cnt = 0;
    for (int k = 0; k < N_OUT / GRP; k++) {
        const float w = W[(size_t)(l + GRP * k) * N_OUT + j];
        cnt += (w != 0.0f) ? 1 : 0;
    }
    int inc = cnt;
#pragma unroll
    for (int d = 1; d < GRP; d <<= 1) {
        int n = __shfl_up(inc, d, 64);
        if (l >= d) inc += n;
    }
    int pos = inc - cnt;
    if (l == GRP - 1) cnts[c] = inc;
    for (int k = 0; k < N_OUT / GRP; k++) {
        const int i = l + GRP * k;
        const float w = W[(size_t)i * N_OUT + j];
        if (w != 0.0f) {
            if (pos < CAP)
                ent[c][pos] = ((unsigned long long)(unsigned)i << 32) | __float_as_uint(w);
            pos++;
        }
    }
    __syncthreads();
    const int ccnt = min(cnts[c], CAP);

    // ---------- this lane's entries -> registers, padded to KMAX ----------
    float wreg[KMAX];
    int   ireg[KMAX];
#pragma unroll
    for (int k = 0; k < KMAX; k++) {
        const int p = l + k * GRP;
        if (p < ccnt) {
            const unsigned long long e = ent[c][p];
            wreg[k] = __uint_as_float((unsigned)e);
            ireg[k] = (int)(e >> 32);
        } else {
            wreg[k] = 0.f;   // pad: gathers vsh[0] (same-addr broadcast), w=0
            ireg[k] = 0;
        }
    }

    // ---------- wave-uniform MAC bound: kmw = max over wave of ceil(ccnt/8) --
    int kmw = (ccnt + GRP - 1) >> 3;
#pragma unroll
    for (int d = 1; d < 64; d <<= 1) {
        const int o = __shfl_xor(kmw, d, 64);
        kmw = (o > kmw) ? o : kmw;
    }
    if (kmw > KMAX) kmw = KMAX;

    // ---------- bank-rotation sort, PADS LAST (r14-verified) ----------
    // real key = ((idx&31) - lane) & 31 (0..31); pad key = 64 -> sorts last,
    // so the first kmw positions contain every real entry.
#pragma unroll
    for (int pass = 0; pass < KMAX; ++pass) {
#pragma unroll
        for (int i = (pass & 1); i + 1 < KMAX; i += 2) {
            const int ka = (wreg[i]     == 0.f) ? 64 : (((ireg[i]     & 31) - lw) & 31);
            const int kb = (wreg[i + 1] == 0.f) ? 64 : (((ireg[i + 1] & 31) - lw) & 31);
            const bool sw = ka > kb;
            const int   ti = sw ? ireg[i] : ireg[i + 1];
            const int   bi = sw ? ireg[i + 1] : ireg[i];
            const float tw = sw ? wreg[i] : wreg[i + 1];
            const float bw = sw ? wreg[i + 1] : wreg[i];
            ireg[i] = bi; ireg[i + 1] = ti;
            wreg[i] = bw; wreg[i + 1] = tw;
        }
    }

    float vold = 0.f;   // leak-term state carried in a register

    // ---------- sequential scan over T ----------
#pragma unroll 1
    for (int t = 0; t < T_STEPS; t++) {
        // gate on the u-producer once per m-tile (uniform, rare, usually open)
        if ((t & 127) == 0) {
            while (__hip_atomic_load(&mcnt[t >> 7], __ATOMIC_ACQUIRE,
                                     __HIP_MEMORY_SCOPE_AGENT) < 16) { }
        }
        // u prefetch BEFORE the poll: its latency rides the poll's wait
        float u = 0.f;
        if (l == 0) u = UO[(size_t)t * N_OUT + j];

        // ---- poll tagged slots for v_t (8 slots/thread, pending-only) -----
        unsigned long long* vin = vslots + (size_t)(t & 1) * N_OUT;
        float* dst = vsh[t & 1];
        unsigned long long uq[8];
#pragma unroll
        for (int q = 0; q < 8; q++)
            uq[q] = __hip_atomic_load(&vin[tid + q * 256], __ATOMIC_RELAXED,
                                      __HIP_MEMORY_SCOPE_AGENT);
        unsigned pend = 0xFFu;
#pragma unroll 1
        while (true) {
            unsigned np = 0;
#pragma unroll
            for (int q = 0; q < 8; q++) {
                if (pend & (1u << q)) {
                    if ((unsigned)(uq[q] >> 32) == (unsigned)t)
                        dst[tid + q * 256] = __uint_as_float((unsigned)uq[q]);
                    else
                        np |= (1u << q);
                }
            }
            pend = np;
            if (!pend) break;
#pragma unroll
            for (int q = 0; q < 8; q++)
                if (pend & (1u << q))
                    uq[q] = __hip_atomic_load(&vin[tid + q * 256], __ATOMIC_RELAXED,
                                              __HIP_MEMORY_SCOPE_AGENT);
        }
        __syncthreads();   // vsh[t&1] complete (single barrier per step)

        // ---- MAC: 20 unconditional + wave-uniform guarded tail chunks -----
        // (compile-time register indices only -> no scratch; pads are last)
        const float* vcur = vsh[t & 1];
        float yy[4] = {0.f, 0.f, 0.f, 0.f};
#define MACK(k) yy[(k) & 3] = fmaf(wreg[(k)], vcur[ireg[(k)]], yy[(k) & 3])
#pragma unroll
        for (int k = 0; k < 20; k += 4) {
            MACK(k + 0); MACK(k + 1); MACK(k + 2); MACK(k + 3);
        }
        if (kmw > 20) { MACK(20); MACK(21); MACK(22); MACK(23); }
        if (kmw > 24) { MACK(24); MACK(25); MACK(26); MACK(27); }
        if (kmw > 28) { MACK(28); MACK(29); MACK(30); MACK(31); }
        if (kmw > 32) { MACK(32); MACK(33); MACK(34); MACK(35); }
#undef MACK
        float y = (yy[0] + yy[1]) + (yy[2] + yy[3]);
#pragma unroll
        for (int d = GRP / 2; d >= 1; d >>= 1) y += __shfl_xor(y, d, 64);

        if (l == 0) {
            const float vnew = 0.5f * vold + 0.5f * fast_tanh(y + u);
            vold = vnew;
            // slot store FIRST (inter-block critical path), then the output
            const unsigned long long slot =
                ((unsigned long long)(unsigned)(t + 1) << 32) | __float_as_uint(vnew);
            __hip_atomic_store(&vslots[(size_t)((t + 1) & 1) * N_OUT + j], slot,
                               __ATOMIC_RELAXED, __HIP_MEMORY_SCOPE_AGENT);
            UO[(size_t)t * N_OUT + j] = vnew;
        }
        // no trailing barrier: next step touches only vsh[(t+1)&1]
        // (producing v_{t+1} requires all of v_t read -> parity reuse safe)
    }
}

// ---------------------------------------------------------------------------
extern "C" void kernel_launch(void* const* d_in, const int* in_sizes, int n_in,
                              void* d_out, int out_size, void* d_ws, size_t ws_size,
                              hipStream_t stream) {
    const float* x   = (const float*)d_in[0];   // [4096, 8192]
    const float* W   = (const float*)d_in[1];   // [2048, 2048]
    const float* Win = (const float*)d_in[2];   // [8192, 2048]
    float* out = (float*)d_out;                 // [4096, 2048]

    unsigned long long* vslots = (unsigned long long*)d_ws;  // 2 x N_OUT x 8B
    int* mcnt = (int*)((char*)d_ws + 2 * N_OUT * sizeof(unsigned long long));

    // zero slots (tag0 = zero state) + m-tile counters, every launch
    hipMemsetAsync(d_ws, 0,
                   2 * N_OUT * sizeof(unsigned long long) + NMT * sizeof(int),
                   stream);

    esn_fused<<<RB + GEMM_BLOCKS, 256, 0, stream>>>(x, W, Win, out, vslots, mcnt);
}